// Round 1
// baseline (637.651 us; speedup 1.0000x reference)
//
#include <hip/hip_runtime.h>
#include <math.h>

#define Sq 256      // sequence length
#define NBb 2       // batch
#define NH 8        // heads
#define ND 32       // head dim
#define TT 256      // total = H*D
#define FF 1024     // ff dim
#define NDIST 513   // 2*MAXSEP+1

// ---------------- helpers ----------------
__device__ __forceinline__ float block_sum_256(float v, float* red) {
  #pragma unroll
  for (int m = 1; m < 64; m <<= 1) v += __shfl_xor(v, m);
  __syncthreads();
  if ((threadIdx.x & 63) == 0) red[threadIdx.x >> 6] = v;
  __syncthreads();
  return red[0] + red[1] + red[2] + red[3];
}

// ---------------- T_g = pe @ W_fus_g (+ b_fus folded into g==0) ----------------
__global__ void k_tables(const float* __restrict__ pe, const float* __restrict__ W_fus,
                         const float* __restrict__ b_fus, float* __restrict__ Tt) {
  int g = blockIdx.x / NDIST;
  int dist = blockIdx.x % NDIST;
  int c = threadIdx.x;
  __shared__ float pr[TT];
  pr[c] = pe[dist * TT + c];
  __syncthreads();
  float acc = (g == 0) ? b_fus[c] : 0.0f;
  const float* w = W_fus + g * TT * TT;
  #pragma unroll 4
  for (int k = 0; k < TT; ++k) acc = fmaf(pr[k], w[k * TT + c], acc);
  Tt[blockIdx.x * TT + c] = acc;
}

// ---------------- generic [M,256]@[256,256]+bias, one row per block ----------------
__global__ void k_gemm256(const float* __restrict__ A, const float* __restrict__ W,
                          const float* __restrict__ bias, float* __restrict__ C) {
  int m = blockIdx.x, n = threadIdx.x;
  __shared__ float ar[TT];
  ar[n] = A[m * TT + n];
  __syncthreads();
  float acc = bias[n];
  #pragma unroll 4
  for (int k = 0; k < TT; ++k) acc = fmaf(ar[k], W[k * TT + n], acc);
  C[m * TT + n] = acc;
}

// ---------------- q projection producing q+u and q+v ----------------
__global__ void k_proj_q(const float* __restrict__ A, const float* __restrict__ W,
                         const float* __restrict__ bias, const float* __restrict__ uvec,
                         const float* __restrict__ vvec, float* __restrict__ QU,
                         float* __restrict__ QV) {
  int m = blockIdx.x, n = threadIdx.x;
  __shared__ float ar[TT];
  ar[n] = A[m * TT + n];
  __syncthreads();
  float acc = bias[n];
  #pragma unroll 4
  for (int k = 0; k < TT; ++k) acc = fmaf(ar[k], W[k * TT + n], acc);
  QU[m * TT + n] = acc + uvec[n];
  QV[m * TT + n] = acc + vvec[n];
}

// ---------------- P[b,i,h,c] = sum_d QV[b,i,h,d] * Wr[c, h*32+d] ----------------
__global__ void k_wrproj(const float* __restrict__ QV, const float* __restrict__ Wr,
                         float* __restrict__ P) {
  int bi = blockIdx.x, c = threadIdx.x;
  __shared__ float qv[TT];
  qv[c] = QV[bi * TT + c];
  __syncthreads();
  const float4* wr = (const float4*)(Wr + c * TT);
  float acc[NH];
  #pragma unroll
  for (int h = 0; h < NH; ++h) {
    float a = 0.f;
    #pragma unroll
    for (int d4 = 0; d4 < ND / 4; ++d4) {
      float4 w4 = wr[h * (ND / 4) + d4];
      const float* q4 = qv + h * ND + d4 * 4;
      a += w4.x * q4[0] + w4.y * q4[1] + w4.z * q4[2] + w4.w * q4[3];
    }
    acc[h] = a;
  }
  #pragma unroll
  for (int h = 0; h < NH; ++h) P[(bi * NH + h) * TT + c] = acc[h];
}

// ---------------- fused score (AC + BD + mask) + softmax + attn*V ----------------
// one block per (b,i); threads: phase 1 -> j, phase 2 -> (h, d)
__global__ void k_attn(const float* __restrict__ QU, const float* __restrict__ QVg,
                       const float* __restrict__ Kb, const float* __restrict__ Vb,
                       const float* __restrict__ P, const float* __restrict__ Tt,
                       const int* __restrict__ pos_s, const int* __restrict__ pos_e,
                       const int* __restrict__ real_lengths, const int* __restrict__ lex_num,
                       const float* __restrict__ br, float* __restrict__ ATT) {
  int bi = blockIdx.x;
  int b = bi / Sq, i = bi % Sq;
  int tid = threadIdx.x;
  __shared__ float qu[TT], qv[TT], brs[TT];
  __shared__ float pl[NH * TT];
  __shared__ float sc[NH][Sq];
  __shared__ float red[NH];
  qu[tid] = QU[bi * TT + tid];
  qv[tid] = QVg[bi * TT + tid];
  brs[tid] = br[tid];
  #pragma unroll
  for (int h = 0; h < NH; ++h) pl[h * TT + tid] = P[(bi * NH + h) * TT + tid];
  __syncthreads();

  int j = tid;
  int psi = pos_s[b * Sq + i], pei = pos_e[b * Sq + i];
  int psj = pos_s[b * Sq + j], pej = pos_e[b * Sq + j];
  const float4* t0 = (const float4*)(Tt + (0 * NDIST + (psi - psj + 256)) * TT);
  const float4* t1 = (const float4*)(Tt + (1 * NDIST + (psi - pej + 256)) * TT);
  const float4* t2 = (const float4*)(Tt + (2 * NDIST + (pei - psj + 256)) * TT);
  const float4* t3 = (const float4*)(Tt + (3 * NDIST + (pei - pej + 256)) * TT);

  float bd[NH];
  #pragma unroll
  for (int h = 0; h < NH; ++h) bd[h] = 0.f;
  for (int c4 = 0; c4 < TT / 4; ++c4) {
    float4 a0 = t0[c4], a1 = t1[c4], a2 = t2[c4], a3 = t3[c4];
    float r0 = fmaxf(a0.x + a1.x + a2.x + a3.x, 0.f);
    float r1 = fmaxf(a0.y + a1.y + a2.y + a3.y, 0.f);
    float r2 = fmaxf(a0.z + a1.z + a2.z + a3.z, 0.f);
    float r3 = fmaxf(a0.w + a1.w + a2.w + a3.w, 0.f);
    #pragma unroll
    for (int h = 0; h < NH; ++h) {
      float4 p4 = *(const float4*)(pl + h * TT + c4 * 4);
      bd[h] += r0 * p4.x + r1 * p4.y + r2 * p4.z + r3 * p4.w;
    }
  }

  const float4* krow = (const float4*)(Kb + (b * Sq + j) * TT);
  int rl = real_lengths[b] + lex_num[0];
  bool valid = (j < rl);
  #pragma unroll
  for (int h = 0; h < NH; ++h) {
    float ac = 0.f, brd = 0.f;
    #pragma unroll
    for (int d4 = 0; d4 < ND / 4; ++d4) {
      float4 k4 = krow[h * (ND / 4) + d4];
      const float* q4 = qu + h * ND + d4 * 4;
      const float* v4 = qv + h * ND + d4 * 4;
      const float* b4 = brs + h * ND + d4 * 4;
      ac += k4.x * q4[0] + k4.y * q4[1] + k4.z * q4[2] + k4.w * q4[3];
      brd += v4[0] * b4[0] + v4[1] * b4[1] + v4[2] * b4[2] + v4[3] * b4[3];
    }
    sc[h][j] = valid ? (ac + bd[h] + brd) : -1e15f;
  }
  __syncthreads();

  // softmax over j for each h
  int h2 = tid >> 5, t = tid & 31;
  float pm = -INFINITY;
  #pragma unroll
  for (int m = 0; m < 8; ++m) pm = fmaxf(pm, sc[h2][t + 32 * m]);
  #pragma unroll
  for (int m = 16; m >= 1; m >>= 1) pm = fmaxf(pm, __shfl_xor(pm, m));
  if (t == 0) red[h2] = pm;
  __syncthreads();
  #pragma unroll
  for (int h = 0; h < NH; ++h) sc[h][tid] = __expf(sc[h][tid] - red[h]);
  __syncthreads();
  float ps = 0.f;
  #pragma unroll
  for (int m = 0; m < 8; ++m) ps += sc[h2][t + 32 * m];
  #pragma unroll
  for (int m = 16; m >= 1; m >>= 1) ps += __shfl_xor(ps, m);
  if (t == 0) red[h2] = ps;
  __syncthreads();

  // attn out: thread tid = h2*32 + d  (n = tid)
  float acc = 0.f;
  for (int jj = 0; jj < Sq; ++jj) acc = fmaf(sc[h2][jj], Vb[(b * Sq + jj) * TT + tid], acc);
  ATT[bi * TT + tid] = acc / red[h2];
}

// ---------------- y = LN(a + b) ----------------
__global__ void k_ln_add(const float* __restrict__ A, const float* __restrict__ Bv,
                         float* __restrict__ Yo) {
  __shared__ float red[4];
  int m = blockIdx.x, tid = threadIdx.x;
  float val = A[m * TT + tid] + Bv[m * TT + tid];
  float s = block_sum_256(val, red);
  float mean = s * (1.0f / TT);
  float d = val - mean;
  float s2 = block_sum_256(d * d, red);
  Yo[m * TT + tid] = d * rsqrtf(s2 * (1.0f / TT) + 1e-5f);
}

// ---------------- h1 = relu(y @ W1 + b1), N=1024 ----------------
__global__ void k_ffn1(const float* __restrict__ Y, const float* __restrict__ W1,
                       const float* __restrict__ b1, float* __restrict__ H1) {
  int m = blockIdx.x, tid = threadIdx.x;
  __shared__ float yr[TT];
  yr[tid] = Y[m * TT + tid];
  __syncthreads();
  float acc0 = b1[tid], acc1 = b1[tid + 256], acc2 = b1[tid + 512], acc3 = b1[tid + 768];
  #pragma unroll 4
  for (int k = 0; k < TT; ++k) {
    float a = yr[k];
    const float* w = W1 + k * FF;
    acc0 = fmaf(a, w[tid], acc0);
    acc1 = fmaf(a, w[tid + 256], acc1);
    acc2 = fmaf(a, w[tid + 512], acc2);
    acc3 = fmaf(a, w[tid + 768], acc3);
  }
  H1[m * FF + tid] = fmaxf(acc0, 0.f);
  H1[m * FF + tid + 256] = fmaxf(acc1, 0.f);
  H1[m * FF + tid + 512] = fmaxf(acc2, 0.f);
  H1[m * FF + tid + 768] = fmaxf(acc3, 0.f);
}

// ---------------- out = LN(relu(h1 @ W2 + b2) + y) ----------------
__global__ void k_ffn2_ln(const float* __restrict__ H1, const float* __restrict__ W2,
                          const float* __restrict__ b2, const float* __restrict__ Y,
                          float* __restrict__ O) {
  int m = blockIdx.x, tid = threadIdx.x;
  __shared__ float hr[FF];
  __shared__ float red[4];
  #pragma unroll
  for (int q = 0; q < 4; ++q) hr[tid + 256 * q] = H1[m * FF + tid + 256 * q];
  __syncthreads();
  float acc = b2[tid];
  #pragma unroll 4
  for (int k = 0; k < FF; ++k) acc = fmaf(hr[k], W2[k * TT + tid], acc);
  float val = fmaxf(acc, 0.f) + Y[m * TT + tid];
  float s = block_sum_256(val, red);
  float mean = s * (1.0f / TT);
  float d = val - mean;
  float s2 = block_sum_256(d * d, red);
  O[m * TT + tid] = d * rsqrtf(s2 * (1.0f / TT) + 1e-5f);
}

extern "C" void kernel_launch(void* const* d_in, const int* in_sizes, int n_in,
                              void* d_out, int out_size, void* d_ws, size_t ws_size,
                              hipStream_t stream) {
  const float* x            = (const float*)d_in[0];
  const int*   pos_s        = (const int*)d_in[1];
  const int*   pos_e        = (const int*)d_in[2];
  const int*   real_lengths = (const int*)d_in[3];
  const int*   lex_num      = (const int*)d_in[4];
  const float* pe           = (const float*)d_in[5];
  const float* W_fus        = (const float*)d_in[6];
  const float* b_fus        = (const float*)d_in[7];
  const float* Wq           = (const float*)d_in[8];
  const float* bq           = (const float*)d_in[9];
  const float* Wk           = (const float*)d_in[10];
  const float* bk           = (const float*)d_in[11];
  const float* Wv           = (const float*)d_in[12];
  const float* bv           = (const float*)d_in[13];
  const float* Wr           = (const float*)d_in[14];
  const float* br           = (const float*)d_in[15];
  const float* u            = (const float*)d_in[16];
  const float* v            = (const float*)d_in[17];
  const float* W1           = (const float*)d_in[18];
  const float* b1           = (const float*)d_in[19];
  const float* W2           = (const float*)d_in[20];
  const float* b2           = (const float*)d_in[21];
  float* out = (float*)d_out;

  float* ws = (float*)d_ws;
  float* Tt  = ws;                 // 4*513*256 = 525312
  float* QU  = Tt + 4 * NDIST * TT;  // 131072 each below
  float* QV  = QU + NBb * Sq * TT;
  float* Kb  = QV + NBb * Sq * TT;
  float* Vb  = Kb + NBb * Sq * TT;
  float* P   = Vb + NBb * Sq * TT;   // 2*256*8*256 = 1048576
  float* ATT = P + NBb * Sq * NH * TT;
  float* Y   = ATT + NBb * Sq * TT;
  float* H1  = Y + NBb * Sq * TT;    // 512*1024
  float* C1  = H1 + NBb * Sq * FF;   // layer-0 output, 131072

  const int M = NBb * Sq;  // 512 rows

  k_tables<<<4 * NDIST, TT, 0, stream>>>(pe, W_fus, b_fus, Tt);

  for (int l = 0; l < 2; ++l) {
    const float* cur = (l == 0) ? x : C1;
    float* outbuf = (l == 0) ? C1 : out;
    const int wo = l * TT * TT;   // 65536
    const int bo = l * TT;        // 256
    k_proj_q<<<M, TT, 0, stream>>>(cur, Wq + wo, bq + bo, u + bo, v + bo, QU, QV);
    k_gemm256<<<M, TT, 0, stream>>>(cur, Wk + wo, bk + bo, Kb);
    k_gemm256<<<M, TT, 0, stream>>>(cur, Wv + wo, bv + bo, Vb);
    k_wrproj<<<M, TT, 0, stream>>>(QV, Wr + wo, P);
    k_attn<<<M, TT, 0, stream>>>(QU, QV, Kb, Vb, P, Tt, pos_s, pos_e,
                                 real_lengths, lex_num, br + bo, ATT);
    k_ln_add<<<M, TT, 0, stream>>>(cur, ATT, Y);
    k_ffn1<<<M, TT, 0, stream>>>(Y, W1 + l * TT * FF, b1 + l * FF, H1);
    k_ffn2_ln<<<M, TT, 0, stream>>>(H1, W2 + l * TT * FF, b2 + bo, Y, outbuf);
  }
}

// Round 2
// 305.956 us; speedup vs baseline: 2.0841x; 2.0841x over previous
//
#include <hip/hip_runtime.h>
#include <math.h>

#define Sq 256
#define NBb 2
#define NH 8
#define ND 32
#define TT 256
#define FF 1024
#define NDIST 513

// ============ setup: Tt tables (4x513x256) + fused Wqr + Pbias ============
// grid 1092 = 4*257 (tables) + 64 (wqr); block 256
__global__ void k_setup(const float* __restrict__ pe, const float* __restrict__ W_fus,
                        const float* __restrict__ b_fus, const float* __restrict__ Wq,
                        const float* __restrict__ Wr, const float* __restrict__ bq,
                        const float* __restrict__ vv, float* __restrict__ Tt,
                        float* __restrict__ Wqr, float* __restrict__ Pbias) {
  __shared__ float lds[2048];
  int bx = blockIdx.x, tid = threadIdx.x;
  if (bx < 4 * 257) {
    int g = bx / 257, dt = bx % 257;
    int d0 = dt * 2;
    bool two = (d0 + 1 < NDIST);
    lds[tid] = pe[d0 * TT + tid];
    lds[256 + tid] = two ? pe[(d0 + 1) * TT + tid] : 0.f;
    __syncthreads();
    float a0 = (g == 0) ? b_fus[tid] : 0.f;
    float a1 = a0;
    const float* w = W_fus + g * TT * TT;
    #pragma unroll 4
    for (int k = 0; k < TT; ++k) {
      float wv = w[k * TT + tid];
      a0 = fmaf(lds[k], wv, a0);
      a1 = fmaf(lds[256 + k], wv, a1);
    }
    Tt[(g * NDIST + d0) * TT + tid] = a0;
    if (two) Tt[(g * NDIST + d0 + 1) * TT + tid] = a1;
  } else {
    int r = bx - 4 * 257;            // 0..63
    int l = r >> 5; r &= 31;
    int h = r >> 2, kt = r & 3, k0 = kt * 64;
    // thread = c; regs: Wr[l][c][h*32+d], d=0..31
    const float4* wrp = (const float4*)(Wr + l * TT * TT + tid * TT + h * ND);
    float4 wr[8];
    #pragma unroll
    for (int q = 0; q < 8; ++q) wr[q] = wrp[q];
    for (int idx = tid; idx < 64 * 32; idx += 256) {
      int kk = idx >> 5, d = idx & 31;
      lds[idx] = Wq[l * TT * TT + (k0 + kk) * TT + h * ND + d];
    }
    __syncthreads();
    for (int kk = 0; kk < 64; ++kk) {
      const float4* wq = (const float4*)(lds + kk * 32);
      float acc = 0.f;
      #pragma unroll
      for (int q = 0; q < 8; ++q) {
        float4 a = wq[q], bb = wr[q];
        acc += a.x * bb.x + a.y * bb.y + a.z * bb.z + a.w * bb.w;
      }
      Wqr[l * 524288 + (k0 + kk) * 2048 + h * TT + tid] = acc;
    }
    if (kt == 0) {
      const float* bqp = bq + l * TT + h * ND;
      const float* vp = vv + l * TT + h * ND;
      float acc = 0.f;
      #pragma unroll
      for (int q = 0; q < 8; ++q) {
        float4 bb = wr[q];
        int d = q * 4;
        acc += (bqp[d] + vp[d]) * bb.x + (bqp[d + 1] + vp[d + 1]) * bb.y +
               (bqp[d + 2] + vp[d + 2]) * bb.z + (bqp[d + 3] + vp[d + 3]) * bb.w;
      }
      Pbias[l * 2048 + h * TT + tid] = acc;
    }
  }
}

// ============ projections: QU, K, V, P in one launch ============
// grid (128, 11): y=0 q(+u), y=1 k, y=2 v, y=3..10 P head h ; 4 rows/block
__global__ void k_proj(const float* __restrict__ cur, const float* __restrict__ Wq,
                       const float* __restrict__ Wk, const float* __restrict__ Wv,
                       const float* __restrict__ Wqr, const float* __restrict__ bq,
                       const float* __restrict__ bk, const float* __restrict__ bv,
                       const float* __restrict__ uu, const float* __restrict__ Pbias,
                       float* __restrict__ QU, float* __restrict__ Kb,
                       float* __restrict__ Vb, float* __restrict__ P) {
  __shared__ float a[4][TT];
  int tid = threadIdx.x;
  int r0 = blockIdx.x * 4;
  int by = blockIdx.y;
  #pragma unroll
  for (int rr = 0; rr < 4; ++rr) a[rr][tid] = cur[(r0 + rr) * TT + tid];
  __syncthreads();
  const float* W; int ld, col, old; float init; float* outp;
  if (by == 0)      { W = Wq;  ld = TT;   col = tid; init = bq[tid] + uu[tid]; outp = QU; old = TT; }
  else if (by == 1) { W = Wk;  ld = TT;   col = tid; init = bk[tid];           outp = Kb; old = TT; }
  else if (by == 2) { W = Wv;  ld = TT;   col = tid; init = bv[tid];           outp = Vb; old = TT; }
  else { int h = by - 3; W = Wqr; ld = 2048; col = h * TT + tid;
         init = Pbias[h * TT + tid]; outp = P; old = 2048; }
  float ac0 = init, ac1 = init, ac2 = init, ac3 = init;
  const float* wp = W + col;
  #pragma unroll 4
  for (int k = 0; k < TT; ++k) {
    float w = wp[k * ld];
    ac0 = fmaf(a[0][k], w, ac0);
    ac1 = fmaf(a[1][k], w, ac1);
    ac2 = fmaf(a[2][k], w, ac2);
    ac3 = fmaf(a[3][k], w, ac3);
  }
  outp[(r0 + 0) * old + col] = ac0;
  outp[(r0 + 1) * old + col] = ac1;
  outp[(r0 + 2) * old + col] = ac2;
  outp[(r0 + 3) * old + col] = ac3;
}

// ============ scores: AC + BD + mask -> SC[bi][h][j] ============
// grid (512, 8); block 256 = 32 j x 8 c-lanes
__global__ void k_score(const float* __restrict__ QU, const float* __restrict__ Kb,
                        const float* __restrict__ P, const float* __restrict__ Tt,
                        const int* __restrict__ pos_s, const int* __restrict__ pos_e,
                        const int* __restrict__ real_lengths, const int* __restrict__ lex_num,
                        float* __restrict__ SC) {
  __shared__ float pl[NH][TT];
  __shared__ float qu[TT];
  __shared__ float scl[NH][32];
  int tid = threadIdx.x;
  int bi = blockIdx.x, b = bi >> 8, i = bi & 255;
  int jc = blockIdx.y;
  int jl = tid >> 3, cl = tid & 7;
  int j = jc * 32 + jl;
  #pragma unroll
  for (int rep = 0; rep < 8; ++rep) {
    int idx = rep * 256 + tid;
    pl[idx >> 8][idx & 255] = P[bi * 2048 + idx];
  }
  qu[tid] = QU[bi * TT + tid];
  __syncthreads();
  int psi = pos_s[b * Sq + i], pei = pos_e[b * Sq + i];
  int psj = pos_s[b * Sq + j], pej = pos_e[b * Sq + j];
  const float4* t0 = (const float4*)(Tt + (0 * NDIST + (psi - psj + 256)) * TT);
  const float4* t1 = (const float4*)(Tt + (1 * NDIST + (psi - pej + 256)) * TT);
  const float4* t2 = (const float4*)(Tt + (2 * NDIST + (pei - psj + 256)) * TT);
  const float4* t3 = (const float4*)(Tt + (3 * NDIST + (pei - pej + 256)) * TT);
  float bd[NH];
  #pragma unroll
  for (int h = 0; h < NH; ++h) bd[h] = 0.f;
  #pragma unroll
  for (int ci = 0; ci < 8; ++ci) {
    int f = ci * 8 + cl;
    float4 a0 = t0[f], a1 = t1[f], a2 = t2[f], a3 = t3[f];
    float r0 = fmaxf(a0.x + a1.x + a2.x + a3.x, 0.f);
    float r1 = fmaxf(a0.y + a1.y + a2.y + a3.y, 0.f);
    float r2 = fmaxf(a0.z + a1.z + a2.z + a3.z, 0.f);
    float r3 = fmaxf(a0.w + a1.w + a2.w + a3.w, 0.f);
    #pragma unroll
    for (int h = 0; h < NH; ++h) {
      float4 p = ((const float4*)pl[h])[f];
      bd[h] += r0 * p.x + r1 * p.y + r2 * p.z + r3 * p.w;
    }
  }
  const float4* kp = (const float4*)(Kb + (b * Sq + j) * TT);
  const float4* qp = (const float4*)qu;
  #pragma unroll
  for (int h = 0; h < NH; ++h) {
    int f = h * 8 + cl;
    float4 k4 = kp[f], q4 = qp[f];
    bd[h] += k4.x * q4.x + k4.y * q4.y + k4.z * q4.z + k4.w * q4.w;
  }
  #pragma unroll
  for (int h = 0; h < NH; ++h) {
    bd[h] += __shfl_xor(bd[h], 1);
    bd[h] += __shfl_xor(bd[h], 2);
    bd[h] += __shfl_xor(bd[h], 4);
  }
  if (cl == 0) {
    #pragma unroll
    for (int h = 0; h < NH; ++h) scl[h][jl] = bd[h];
  }
  __syncthreads();
  int rl = real_lengths[b] + lex_num[0];
  int h = tid >> 5, jj = tid & 31;
  int j2 = jc * 32 + jj;
  SC[bi * 2048 + h * TT + j2] = (j2 < rl) ? scl[h][jj] : -1e15f;
}

// ============ softmax + attn*V + residual + LN ============
// grid 512, block 512
__global__ void k_smav_ln(const float* __restrict__ SC, const float* __restrict__ Vb,
                          const float* __restrict__ cur, float* __restrict__ Y) {
  __shared__ float sc[NH][TT];
  __shared__ float inv[NH];
  __shared__ float av[2][TT];
  __shared__ float red2[4];
  int tid = threadIdx.x;
  int bi = blockIdx.x, b = bi >> 8;
  #pragma unroll
  for (int rep = 0; rep < 4; ++rep) {
    int idx = rep * 512 + tid;
    ((float*)sc)[idx] = SC[bi * 2048 + idx];
  }
  __syncthreads();
  int w = tid >> 6, t = tid & 63;
  float x0 = sc[w][t], x1 = sc[w][t + 64], x2 = sc[w][t + 128], x3 = sc[w][t + 192];
  float m = fmaxf(fmaxf(x0, x1), fmaxf(x2, x3));
  #pragma unroll
  for (int sh = 32; sh >= 1; sh >>= 1) m = fmaxf(m, __shfl_xor(m, sh));
  float e0 = __expf(x0 - m), e1 = __expf(x1 - m), e2 = __expf(x2 - m), e3 = __expf(x3 - m);
  sc[w][t] = e0; sc[w][t + 64] = e1; sc[w][t + 128] = e2; sc[w][t + 192] = e3;
  float s = e0 + e1 + e2 + e3;
  #pragma unroll
  for (int sh = 32; sh >= 1; sh >>= 1) s += __shfl_xor(s, sh);
  if (t == 0) inv[w] = 1.f / s;
  __syncthreads();
  int n = tid & 255, jg = tid >> 8, h = n >> 5;
  float acc = 0.f;
  const float* vp = Vb + b * Sq * TT + n;
  #pragma unroll 4
  for (int jj = jg * 128; jj < jg * 128 + 128; ++jj) acc = fmaf(sc[h][jj], vp[jj * TT], acc);
  av[jg][n] = acc;
  __syncthreads();
  float val = 0.f;
  if (tid < 256) {
    float o = (av[0][n] + av[1][n]) * inv[h];
    val = cur[bi * TT + n] + o;
    float ss = val;
    #pragma unroll
    for (int sh = 32; sh >= 1; sh >>= 1) ss += __shfl_xor(ss, sh);
    if ((tid & 63) == 0) red2[tid >> 6] = ss;
  }
  __syncthreads();
  float mean = (red2[0] + red2[1] + red2[2] + red2[3]) * (1.f / TT);
  float d = val - mean;
  __syncthreads();
  if (tid < 256) {
    float ss = d * d;
    #pragma unroll
    for (int sh = 32; sh >= 1; sh >>= 1) ss += __shfl_xor(ss, sh);
    if ((tid & 63) == 0) red2[tid >> 6] = ss;
  }
  __syncthreads();
  if (tid < 256) {
    float var = (red2[0] + red2[1] + red2[2] + red2[3]) * (1.f / TT);
    Y[bi * TT + n] = d * rsqrtf(var + 1e-5f);
  }
}

// ============ FFN1: relu(Y@W1+b1), grid (256,4), 2 rows/block ============
__global__ void k_ffn1(const float* __restrict__ Y, const float* __restrict__ W1,
                       const float* __restrict__ b1, float* __restrict__ H1) {
  __shared__ float a[2][TT];
  int tid = threadIdx.x;
  int r0 = blockIdx.x * 2;
  int n = blockIdx.y * 256 + tid;
  a[0][tid] = Y[r0 * TT + tid];
  a[1][tid] = Y[(r0 + 1) * TT + tid];
  __syncthreads();
  float ac0 = b1[n], ac1 = ac0;
  const float* wp = W1 + n;
  #pragma unroll 4
  for (int k = 0; k < TT; ++k) {
    float w = wp[k * FF];
    ac0 = fmaf(a[0][k], w, ac0);
    ac1 = fmaf(a[1][k], w, ac1);
  }
  H1[r0 * FF + n] = fmaxf(ac0, 0.f);
  H1[(r0 + 1) * FF + n] = fmaxf(ac1, 0.f);
}

// ============ FFN2 + relu + residual + LN ; grid 512, block 512 (K split) ====
__global__ void k_ffn2_ln(const float* __restrict__ H1, const float* __restrict__ W2,
                          const float* __restrict__ b2, const float* __restrict__ Y,
                          float* __restrict__ O) {
  __shared__ float hr[FF];
  __shared__ float part[2][TT];
  __shared__ float red2[4];
  int tid = threadIdx.x;
  int m = blockIdx.x;
  hr[tid] = H1[m * FF + tid];
  hr[tid + 512] = H1[m * FF + tid + 512];
  __syncthreads();
  int n = tid & 255, kg = tid >> 8;
  float acc = 0.f;
  const float* wp = W2 + n;
  #pragma unroll 4
  for (int k = kg * 512; k < kg * 512 + 512; ++k) acc = fmaf(hr[k], wp[k * TT], acc);
  part[kg][n] = acc;
  __syncthreads();
  float val = 0.f;
  if (tid < 256) {
    float s = part[0][n] + part[1][n] + b2[n];
    val = fmaxf(s, 0.f) + Y[m * TT + n];
    float ss = val;
    #pragma unroll
    for (int sh = 32; sh >= 1; sh >>= 1) ss += __shfl_xor(ss, sh);
    if ((tid & 63) == 0) red2[tid >> 6] = ss;
  }
  __syncthreads();
  float mean = (red2[0] + red2[1] + red2[2] + red2[3]) * (1.f / TT);
  float d = val - mean;
  __syncthreads();
  if (tid < 256) {
    float ss = d * d;
    #pragma unroll
    for (int sh = 32; sh >= 1; sh >>= 1) ss += __shfl_xor(ss, sh);
    if ((tid & 63) == 0) red2[tid >> 6] = ss;
  }
  __syncthreads();
  if (tid < 256) {
    float var = (red2[0] + red2[1] + red2[2] + red2[3]) * (1.f / TT);
    O[m * TT + n] = d * rsqrtf(var + 1e-5f);
  }
}

extern "C" void kernel_launch(void* const* d_in, const int* in_sizes, int n_in,
                              void* d_out, int out_size, void* d_ws, size_t ws_size,
                              hipStream_t stream) {
  const float* x            = (const float*)d_in[0];
  const int*   pos_s        = (const int*)d_in[1];
  const int*   pos_e        = (const int*)d_in[2];
  const int*   real_lengths = (const int*)d_in[3];
  const int*   lex_num      = (const int*)d_in[4];
  const float* pe           = (const float*)d_in[5];
  const float* W_fus        = (const float*)d_in[6];
  const float* b_fus        = (const float*)d_in[7];
  const float* Wq           = (const float*)d_in[8];
  const float* bq           = (const float*)d_in[9];
  const float* Wk           = (const float*)d_in[10];
  const float* bk           = (const float*)d_in[11];
  const float* Wv           = (const float*)d_in[12];
  const float* bv           = (const float*)d_in[13];
  const float* Wr           = (const float*)d_in[14];
  // br (d_in[15]) dropped: per-(b,i,h) constant shift, softmax-invariant
  const float* u            = (const float*)d_in[16];
  const float* v            = (const float*)d_in[17];
  const float* W1           = (const float*)d_in[18];
  const float* b1           = (const float*)d_in[19];
  const float* W2           = (const float*)d_in[20];
  const float* b2           = (const float*)d_in[21];
  float* out = (float*)d_out;

  float* ws    = (float*)d_ws;
  float* Tt    = ws;                  // 4*513*256 = 525312
  float* Wqr   = Tt + 525312;         // 2*256*2048 = 1048576
  float* Pbias = Wqr + 1048576;       // 2*2048 = 4096
  float* QU    = Pbias + 4096;        // 131072
  float* Kb    = QU + 131072;         // 131072
  float* Vb    = Kb + 131072;         // 131072
  float* P     = Vb + 131072;         // 512*2048 = 1048576
  float* SC    = P + 1048576;         // 1048576 (H1 aliases first half)
  float* H1    = SC;                  // 524288, disjoint in time from SC use
  float* Y     = SC + 1048576;        // 131072
  float* C1    = Y + 131072;          // 131072

  k_setup<<<4 * 257 + 64, 256, 0, stream>>>(pe, W_fus, b_fus, Wq, Wr, bq, v, Tt, Wqr, Pbias);

  for (int l = 0; l < 2; ++l) {
    const float* cur = l ? C1 : x;
    float* outb = l ? out : C1;
    const int wo = l * TT * TT, bo = l * TT;
    k_proj<<<dim3(128, 11), 256, 0, stream>>>(cur, Wq + wo, Wk + wo, Wv + wo,
                                              Wqr + l * 524288, bq + bo, bk + bo, bv + bo,
                                              u + bo, Pbias + l * 2048, QU, Kb, Vb, P);
    k_score<<<dim3(512, 8), 256, 0, stream>>>(QU, Kb, P, Tt, pos_s, pos_e,
                                              real_lengths, lex_num, SC);
    k_smav_ln<<<512, 512, 0, stream>>>(SC, Vb, cur, Y);
    k_ffn1<<<dim3(256, 4), 256, 0, stream>>>(Y, W1 + l * TT * FF, b1 + l * FF, H1);
    k_ffn2_ln<<<512, 512, 0, stream>>>(H1, W2 + l * FF * TT, b2 + bo, Y, outb);
  }
}

// Round 4
// 153.453 us; speedup vs baseline: 4.1553x; 1.9938x over previous
//
#include <hip/hip_runtime.h>
#include <hip/hip_fp16.h>
#include <math.h>

#define Sq 256
#define NH 8
#define ND 32
#define TT 256
#define FF 1024
#define NDIST 513

union H8 { uint4 u4; __half2 h2[4]; };

// ======== tables: Tt[g][d][c] (f16) = (pe @ W_fus_g + (g==0)*b_fus) ========
// grid 260 = 65 rowtiles x 4 g ; block 256 = 64 cg x 4 ks
__global__ void k_tables(const float* __restrict__ pe, const float* __restrict__ W_fus,
                         const float* __restrict__ b_fus, __half* __restrict__ Tt) {
  __shared__ float ldsA[8 * 256];
  __shared__ float red[4 * 8 * 256];
  int bx = blockIdx.x, tid = threadIdx.x;
  int g = bx & 3, rt = bx >> 2;
  int r0 = rt * 8;
  #pragma unroll
  for (int t = 0; t < 8; ++t) {
    int idx = t * 256 + tid, r = idx >> 8, c = idx & 255;
    int row = r0 + r;
    ldsA[idx] = (row < NDIST) ? pe[row * 256 + c] : 0.f;
  }
  __syncthreads();
  int cg = tid & 63, ks = tid >> 6;
  const float4* wp = (const float4*)(W_fus + g * 65536) + ks * 4096 + cg;
  float acc[8][4];
  #pragma unroll
  for (int r = 0; r < 8; ++r) { acc[r][0] = acc[r][1] = acc[r][2] = acc[r][3] = 0.f; }
  #pragma unroll 4
  for (int kk = 0; kk < 64; ++kk) {
    float4 b4 = wp[kk * 64];
    #pragma unroll
    for (int r = 0; r < 8; ++r) {
      float a = ldsA[r * 256 + ks * 64 + kk];
      acc[r][0] = fmaf(a, b4.x, acc[r][0]);
      acc[r][1] = fmaf(a, b4.y, acc[r][1]);
      acc[r][2] = fmaf(a, b4.z, acc[r][2]);
      acc[r][3] = fmaf(a, b4.w, acc[r][3]);
    }
  }
  #pragma unroll
  for (int r = 0; r < 8; ++r)
    *(float4*)(red + ks * 2048 + r * 256 + cg * 4) =
        make_float4(acc[r][0], acc[r][1], acc[r][2], acc[r][3]);
  __syncthreads();
  float bb = (g == 0) ? b_fus[tid] : 0.f;
  #pragma unroll
  for (int r = 0; r < 8; ++r) {
    int row = r0 + r;
    if (row < NDIST) {
      float v = bb + red[r * 256 + tid] + red[2048 + r * 256 + tid] +
                red[4096 + r * 256 + tid] + red[6144 + r * 256 + tid];
      Tt[(g * NDIST + row) * 256 + tid] = __float2half(v);
    }
  }
}

// ======== projections q(->QU,QV), k, v ; grid (64, 3) ========
__global__ void k_proj(const float* __restrict__ cur, const float* __restrict__ Wq,
                       const float* __restrict__ Wk, const float* __restrict__ Wv,
                       const float* __restrict__ bq, const float* __restrict__ bk,
                       const float* __restrict__ bv, const float* __restrict__ uu,
                       const float* __restrict__ vv, float* __restrict__ QU,
                       float* __restrict__ QV, float* __restrict__ Kb,
                       float* __restrict__ Vb) {
  __shared__ float ldsA[8 * 256];
  __shared__ float red[4 * 8 * 256];
  int tid = threadIdx.x;
  int r0 = blockIdx.x * 8;
  int by = blockIdx.y;
  const float* W = (by == 0) ? Wq : (by == 1) ? Wk : Wv;
  #pragma unroll
  for (int t = 0; t < 8; ++t) {
    int idx = t * 256 + tid, r = idx >> 8, c = idx & 255;
    ldsA[idx] = cur[(r0 + r) * 256 + c];
  }
  __syncthreads();
  int cg = tid & 63, ks = tid >> 6;
  const float4* wp = (const float4*)W + ks * 4096 + cg;
  float acc[8][4];
  #pragma unroll
  for (int r = 0; r < 8; ++r) { acc[r][0] = acc[r][1] = acc[r][2] = acc[r][3] = 0.f; }
  #pragma unroll 4
  for (int kk = 0; kk < 64; ++kk) {
    float4 b4 = wp[kk * 64];
    #pragma unroll
    for (int r = 0; r < 8; ++r) {
      float a = ldsA[r * 256 + ks * 64 + kk];
      acc[r][0] = fmaf(a, b4.x, acc[r][0]);
      acc[r][1] = fmaf(a, b4.y, acc[r][1]);
      acc[r][2] = fmaf(a, b4.z, acc[r][2]);
      acc[r][3] = fmaf(a, b4.w, acc[r][3]);
    }
  }
  #pragma unroll
  for (int r = 0; r < 8; ++r)
    *(float4*)(red + ks * 2048 + r * 256 + cg * 4) =
        make_float4(acc[r][0], acc[r][1], acc[r][2], acc[r][3]);
  __syncthreads();
  #pragma unroll
  for (int r = 0; r < 8; ++r) {
    int row = r0 + r;
    float s = red[r * 256 + tid] + red[2048 + r * 256 + tid] +
              red[4096 + r * 256 + tid] + red[6144 + r * 256 + tid];
    if (by == 0) {
      float base = s + bq[tid];
      QU[row * 256 + tid] = base + uu[tid];
      QV[row * 256 + tid] = base + vv[tid];
    } else if (by == 1) {
      Kb[row * 256 + tid] = s + bk[tid];
    } else {
      Vb[row * 256 + tid] = s + bv[tid];
    }
  }
}

// ======== P[bi][h*256+c] (f16) = sum_d QV[bi][h*32+d] * Wr[c][h*32+d] ========
// grid (64 rowtiles, 8 heads); block 256
__global__ void k_p(const float* __restrict__ QV, const float* __restrict__ Wr,
                    __half* __restrict__ P) {
  __shared__ float ldsB[32 * 257];  // [d][c] padded
  __shared__ float ldsA[8 * 32];
  int rt = blockIdx.x, h = blockIdx.y, tid = threadIdx.x;
  int r0 = rt * 8;
  #pragma unroll
  for (int pass = 0; pass < 8; ++pass) {
    int c = pass * 32 + (tid >> 3), q = tid & 7;
    float4 w4 = ((const float4*)(Wr + c * 256 + h * 32))[q];
    ldsB[(q * 4 + 0) * 257 + c] = w4.x;
    ldsB[(q * 4 + 1) * 257 + c] = w4.y;
    ldsB[(q * 4 + 2) * 257 + c] = w4.z;
    ldsB[(q * 4 + 3) * 257 + c] = w4.w;
  }
  { int r = tid >> 5, d = tid & 31; ldsA[r * 32 + d] = QV[(r0 + r) * 256 + h * 32 + d]; }
  __syncthreads();
  int c = tid;
  float acc[8] = {0, 0, 0, 0, 0, 0, 0, 0};
  #pragma unroll 4
  for (int d = 0; d < 32; ++d) {
    float b = ldsB[d * 257 + c];
    #pragma unroll
    for (int r = 0; r < 8; ++r) acc[r] = fmaf(ldsA[r * 32 + d], b, acc[r]);
  }
  #pragma unroll
  for (int r = 0; r < 8; ++r) P[(r0 + r) * 2048 + h * 256 + c] = __float2half(acc[r]);
}

// ======== scores: AC + BD + mask -> SC[bi][h][j] ; grid (512, 8) ========
__global__ void k_score(const float* __restrict__ QU, const float* __restrict__ Kb,
                        const __half* __restrict__ P, const __half* __restrict__ Tt,
                        const int* __restrict__ pos_s, const int* __restrict__ pos_e,
                        const int* __restrict__ real_lengths, const int* __restrict__ lex_num,
                        float* __restrict__ SC) {
  __shared__ __align__(16) __half plh[2048];
  __shared__ float qu[256];
  __shared__ float scl[NH][32];
  int tid = threadIdx.x;
  int bi = blockIdx.x, b = bi >> 8, i = bi & 255;
  int jc = blockIdx.y;
  ((uint4*)plh)[tid] = ((const uint4*)(P + bi * 2048))[tid];
  qu[tid] = QU[bi * 256 + tid];
  __syncthreads();
  int jl = tid >> 3, cl = tid & 7;
  int j = jc * 32 + jl;
  int psi = pos_s[b * Sq + i], pei = pos_e[b * Sq + i];
  int psj = pos_s[b * Sq + j], pej = pos_e[b * Sq + j];
  const __half* t0 = Tt + (0 * NDIST + (psi - psj + 256)) * 256;
  const __half* t1 = Tt + (1 * NDIST + (psi - pej + 256)) * 256;
  const __half* t2 = Tt + (2 * NDIST + (pei - psj + 256)) * 256;
  const __half* t3 = Tt + (3 * NDIST + (pei - pej + 256)) * 256;
  __half2 z2 = __float2half2_rn(0.f);
  __half2 acc2[NH];
  #pragma unroll
  for (int h = 0; h < NH; ++h) acc2[h] = z2;
  #pragma unroll
  for (int ci = 0; ci < 4; ++ci) {
    int c0 = (ci * 8 + cl) * 8;
    H8 A0, A1, A2, A3;
    A0.u4 = *(const uint4*)(t0 + c0);
    A1.u4 = *(const uint4*)(t1 + c0);
    A2.u4 = *(const uint4*)(t2 + c0);
    A3.u4 = *(const uint4*)(t3 + c0);
    __half2 r2[4];
    #pragma unroll
    for (int p = 0; p < 4; ++p) {
      __half2 s = __hadd2(__hadd2(A0.h2[p], A1.h2[p]), __hadd2(A2.h2[p], A3.h2[p]));
      r2[p] = __hmul2(s, __hgt2(s, z2));   // half2 relu (hmax2 overload broken on this ROCm)
    }
    #pragma unroll
    for (int h = 0; h < NH; ++h) {
      H8 Ph;
      Ph.u4 = *(const uint4*)(plh + h * 256 + c0);
      #pragma unroll
      for (int p = 0; p < 4; ++p) acc2[h] = __hfma2(r2[p], Ph.h2[p], acc2[h]);
    }
  }
  const float4* kp = (const float4*)(Kb + (b * Sq + j) * 256);
  float bd[NH];
  #pragma unroll
  for (int h = 0; h < NH; ++h) {
    bd[h] = __low2float(acc2[h]) + __high2float(acc2[h]);
    float4 k4 = kp[h * 8 + cl];
    float4 q4 = *(const float4*)(qu + h * 32 + cl * 4);
    bd[h] += k4.x * q4.x + k4.y * q4.y + k4.z * q4.z + k4.w * q4.w;
  }
  #pragma unroll
  for (int h = 0; h < NH; ++h) {
    bd[h] += __shfl_xor(bd[h], 1);
    bd[h] += __shfl_xor(bd[h], 2);
    bd[h] += __shfl_xor(bd[h], 4);
  }
  if (cl == 0) {
    #pragma unroll
    for (int h = 0; h < NH; ++h) scl[h][jl] = bd[h];
  }
  __syncthreads();
  int rl = real_lengths[b] + lex_num[0];
  int h = tid >> 5, jj = tid & 31;
  int j2 = jc * 32 + jj;
  SC[bi * 2048 + h * 256 + j2] = (j2 < rl) ? scl[h][jj] : -1e15f;
}

// ======== softmax + attn*V + residual + LN ; grid 512, block 256 ========
__global__ void k_smav_ln(const float* __restrict__ SC, const float* __restrict__ Vb,
                          const float* __restrict__ cur, float* __restrict__ Y) {
  __shared__ float sc[2048];
  __shared__ float inv[NH];
  __shared__ float part[4 * 256];
  __shared__ float red2[4];
  int tid = threadIdx.x;
  int bi = blockIdx.x, b = bi >> 8;
  ((float4*)sc)[tid] = ((const float4*)(SC + bi * 2048))[tid];
  ((float4*)sc)[256 + tid] = ((const float4*)(SC + bi * 2048))[256 + tid];
  __syncthreads();
  {
    int h = tid >> 5, t = tid & 31;
    float mx = -INFINITY;
    #pragma unroll
    for (int m = 0; m < 8; ++m) mx = fmaxf(mx, sc[h * 256 + t + 32 * m]);
    #pragma unroll
    for (int sh = 16; sh >= 1; sh >>= 1) mx = fmaxf(mx, __shfl_xor(mx, sh));
    float sum = 0.f;
    #pragma unroll
    for (int m = 0; m < 8; ++m) {
      float e = __expf(sc[h * 256 + t + 32 * m] - mx);
      sc[h * 256 + t + 32 * m] = e;
      sum += e;
    }
    #pragma unroll
    for (int sh = 16; sh >= 1; sh >>= 1) sum += __shfl_xor(sum, sh);
    if (t == 0) inv[h] = 1.f / sum;
  }
  __syncthreads();
  {
    int n4 = tid & 63, jg = tid >> 6, h = n4 >> 3;
    const float4* vp = (const float4*)(Vb + b * 65536) + n4;
    float4 acc = make_float4(0.f, 0.f, 0.f, 0.f);
    #pragma unroll 4
    for (int jj0 = 0; jj0 < 64; ++jj0) {
      int jj = jg * 64 + jj0;
      float s = sc[h * 256 + jj];
      float4 v4 = vp[jj * 64];
      acc.x = fmaf(s, v4.x, acc.x);
      acc.y = fmaf(s, v4.y, acc.y);
      acc.z = fmaf(s, v4.z, acc.z);
      acc.w = fmaf(s, v4.w, acc.w);
    }
    *(float4*)(part + jg * 256 + n4 * 4) = acc;
  }
  __syncthreads();
  int n = tid;
  float o = part[n] + part[256 + n] + part[512 + n] + part[768 + n];
  float val = cur[bi * 256 + n] + o * inv[n >> 5];
  float ss = val;
  #pragma unroll
  for (int sh = 32; sh >= 1; sh >>= 1) ss += __shfl_xor(ss, sh);
  if ((tid & 63) == 0) red2[tid >> 6] = ss;
  __syncthreads();
  float mean = (red2[0] + red2[1] + red2[2] + red2[3]) * (1.f / 256.f);
  float d = val - mean;
  float s2 = d * d;
  __syncthreads();
  #pragma unroll
  for (int sh = 32; sh >= 1; sh >>= 1) s2 += __shfl_xor(s2, sh);
  if ((tid & 63) == 0) red2[tid >> 6] = s2;
  __syncthreads();
  float var = (red2[0] + red2[1] + red2[2] + red2[3]) * (1.f / 256.f);
  Y[bi * 256 + n] = d * rsqrtf(var + 1e-5f);
}

// ======== FFN1: relu(Y@W1+b1) ; grid (64, 4 colchunks) ========
__global__ void k_ffn1(const float* __restrict__ Y, const float* __restrict__ W1,
                       const float* __restrict__ b1, float* __restrict__ H1) {
  __shared__ float ldsA[8 * 256];
  __shared__ float red[4 * 8 * 256];
  int tid = threadIdx.x;
  int r0 = blockIdx.x * 8, by = blockIdx.y;
  #pragma unroll
  for (int t = 0; t < 8; ++t) {
    int idx = t * 256 + tid, r = idx >> 8, c = idx & 255;
    ldsA[idx] = Y[(r0 + r) * 256 + c];
  }
  __syncthreads();
  int cg = tid & 63, ks = tid >> 6;
  const float4* wp = (const float4*)(W1 + by * 256) + ks * 16384 + cg;
  float acc[8][4];
  #pragma unroll
  for (int r = 0; r < 8; ++r) { acc[r][0] = acc[r][1] = acc[r][2] = acc[r][3] = 0.f; }
  #pragma unroll 4
  for (int kk = 0; kk < 64; ++kk) {
    float4 b4 = wp[kk * 256];
    #pragma unroll
    for (int r = 0; r < 8; ++r) {
      float a = ldsA[r * 256 + ks * 64 + kk];
      acc[r][0] = fmaf(a, b4.x, acc[r][0]);
      acc[r][1] = fmaf(a, b4.y, acc[r][1]);
      acc[r][2] = fmaf(a, b4.z, acc[r][2]);
      acc[r][3] = fmaf(a, b4.w, acc[r][3]);
    }
  }
  #pragma unroll
  for (int r = 0; r < 8; ++r)
    *(float4*)(red + ks * 2048 + r * 256 + cg * 4) =
        make_float4(acc[r][0], acc[r][1], acc[r][2], acc[r][3]);
  __syncthreads();
  int n = by * 256 + tid;
  float bb = b1[n];
  #pragma unroll
  for (int r = 0; r < 8; ++r) {
    float s = bb + red[r * 256 + tid] + red[2048 + r * 256 + tid] +
              red[4096 + r * 256 + tid] + red[6144 + r * 256 + tid];
    H1[(r0 + r) * 1024 + n] = fmaxf(s, 0.f);
  }
}

// ======== FFN2 partial: grid (64 rowtiles, 4 kchunks) ========
__global__ void k_ffn2(const float* __restrict__ H1, const float* __restrict__ W2,
                       float* __restrict__ Pbuf) {
  __shared__ float ldsA[8 * 256];
  __shared__ float red[4 * 8 * 256];
  int tid = threadIdx.x;
  int r0 = blockIdx.x * 8, by = blockIdx.y;
  #pragma unroll
  for (int t = 0; t < 8; ++t) {
    int idx = t * 256 + tid, r = idx >> 8, c = idx & 255;
    ldsA[idx] = H1[(r0 + r) * 1024 + by * 256 + c];
  }
  __syncthreads();
  int cg = tid & 63, ks = tid >> 6;
  const float4* wp = (const float4*)(W2 + by * 256 * 256) + ks * 4096 + cg;
  float acc[8][4];
  #pragma unroll
  for (int r = 0; r < 8; ++r) { acc[r][0] = acc[r][1] = acc[r][2] = acc[r][3] = 0.f; }
  #pragma unroll 4
  for (int kk = 0; kk < 64; ++kk) {
    float4 b4 = wp[kk * 64];
    #pragma unroll
    for (int r = 0; r < 8; ++r) {
      float a = ldsA[r * 256 + ks * 64 + kk];
      acc[r][0] = fmaf(a, b4.x, acc[r][0]);
      acc[r][1] = fmaf(a, b4.y, acc[r][1]);
      acc[r][2] = fmaf(a, b4.z, acc[r][2]);
      acc[r][3] = fmaf(a, b4.w, acc[r][3]);
    }
  }
  #pragma unroll
  for (int r = 0; r < 8; ++r)
    *(float4*)(red + ks * 2048 + r * 256 + cg * 4) =
        make_float4(acc[r][0], acc[r][1], acc[r][2], acc[r][3]);
  __syncthreads();
  #pragma unroll
  for (int r = 0; r < 8; ++r) {
    float s = red[r * 256 + tid] + red[2048 + r * 256 + tid] +
              red[4096 + r * 256 + tid] + red[6144 + r * 256 + tid];
    Pbuf[by * 131072 + (r0 + r) * 256 + tid] = s;
  }
}

// ======== FFN2 reduce + relu + residual + LN ; grid 512, block 256 ========
__global__ void k_ffn2red_ln(const float* __restrict__ Pbuf, const float* __restrict__ b2,
                             const float* __restrict__ Y, float* __restrict__ O) {
  __shared__ float red2[4];
  int m = blockIdx.x, tid = threadIdx.x;
  float s = Pbuf[m * 256 + tid] + Pbuf[131072 + m * 256 + tid] +
            Pbuf[262144 + m * 256 + tid] + Pbuf[393216 + m * 256 + tid] + b2[tid];
  float val = fmaxf(s, 0.f) + Y[m * 256 + tid];
  float ss = val;
  #pragma unroll
  for (int sh = 32; sh >= 1; sh >>= 1) ss += __shfl_xor(ss, sh);
  if ((tid & 63) == 0) red2[tid >> 6] = ss;
  __syncthreads();
  float mean = (red2[0] + red2[1] + red2[2] + red2[3]) * (1.f / 256.f);
  float d = val - mean;
  float s2 = d * d;
  __syncthreads();
  #pragma unroll
  for (int sh = 32; sh >= 1; sh >>= 1) s2 += __shfl_xor(s2, sh);
  if ((tid & 63) == 0) red2[tid >> 6] = s2;
  __syncthreads();
  float var = (red2[0] + red2[1] + red2[2] + red2[3]) * (1.f / 256.f);
  O[m * 256 + tid] = d * rsqrtf(var + 1e-5f);
}

extern "C" void kernel_launch(void* const* d_in, const int* in_sizes, int n_in,
                              void* d_out, int out_size, void* d_ws, size_t ws_size,
                              hipStream_t stream) {
  const float* x            = (const float*)d_in[0];
  const int*   pos_s        = (const int*)d_in[1];
  const int*   pos_e        = (const int*)d_in[2];
  const int*   real_lengths = (const int*)d_in[3];
  const int*   lex_num      = (const int*)d_in[4];
  const float* pe           = (const float*)d_in[5];
  const float* W_fus        = (const float*)d_in[6];
  const float* b_fus        = (const float*)d_in[7];
  const float* Wq           = (const float*)d_in[8];
  const float* bq           = (const float*)d_in[9];
  const float* Wk           = (const float*)d_in[10];
  const float* bk           = (const float*)d_in[11];
  const float* Wv           = (const float*)d_in[12];
  const float* bv           = (const float*)d_in[13];
  const float* Wr           = (const float*)d_in[14];
  // br dropped: per-(b,i,h) constant score shift, softmax-invariant
  const float* u            = (const float*)d_in[16];
  const float* v            = (const float*)d_in[17];
  const float* W1           = (const float*)d_in[18];
  const float* b1           = (const float*)d_in[19];
  const float* W2           = (const float*)d_in[20];
  const float* b2           = (const float*)d_in[21];
  float* out = (float*)d_out;

  float* ws = (float*)d_ws;
  __half* Tt = (__half*)ws;                 // 525312 halfs -> 262656 floats
  float* QU  = ws + 262656;
  float* QV  = QU + 131072;
  float* Kb  = QV + 131072;
  float* Vb  = Kb + 131072;
  __half* P  = (__half*)(Vb + 131072);      // 1048576 halfs -> 524288 floats
  float* SC  = Vb + 131072 + 524288;        // 1048576 floats
  float* Y   = SC + 1048576;
  float* C1  = Y + 131072;
  float* H1  = C1 + 131072;                 // 524288
  float* Pb  = H1 + 524288;                 // 524288

  k_tables<<<260, 256, 0, stream>>>(pe, W_fus, b_fus, Tt);

  for (int l = 0; l < 2; ++l) {
    const float* cur = l ? C1 : x;
    float* outb = l ? out : C1;
    const int wo = l * 65536, bo = l * 256;
    k_proj<<<dim3(64, 3), 256, 0, stream>>>(cur, Wq + wo, Wk + wo, Wv + wo,
                                            bq + bo, bk + bo, bv + bo, u + bo, v + bo,
                                            QU, QV, Kb, Vb);
    k_p<<<dim3(64, 8), 256, 0, stream>>>(QV, Wr + wo, P);
    k_score<<<dim3(512, 8), 256, 0, stream>>>(QU, Kb, P, Tt, pos_s, pos_e,
                                              real_lengths, lex_num, SC);
    k_smav_ln<<<512, 256, 0, stream>>>(SC, Vb, cur, Y);
    k_ffn1<<<dim3(64, 4), 256, 0, stream>>>(Y, W1 + l * 262144, b1 + l * 1024, H1);
    k_ffn2<<<dim3(64, 4), 256, 0, stream>>>(H1, W2 + l * 262144, Pb);
    k_ffn2red_ln<<<512, 256, 0, stream>>>(Pb, b2 + bo, Y, outb);
  }
}

// Round 5
// 114.794 us; speedup vs baseline: 5.5547x; 1.3368x over previous
//
#include <hip/hip_runtime.h>
#include <hip/hip_fp16.h>
#include <math.h>

#define Sq 256
#define NH 8
#define ND 32
#define TT 256
#define FF 1024
#define NDIST 513

union H8 { uint4 u4; __half2 h2[4]; };

// ======== tables: Tt[g][d][c] (f16) = (pe @ W_fus_g + (g==0)*b_fus) ========
// grid 516 = 129 rowtiles(4 rows) x 4 g ; block 256 = 64 cg x 4 ks
__global__ void k_tables(const float* __restrict__ pe, const float* __restrict__ W_fus,
                         const float* __restrict__ b_fus, __half* __restrict__ Tt) {
  __shared__ float ldsA[4 * 256];
  __shared__ float red[4 * 4 * 256];
  int bx = blockIdx.x, tid = threadIdx.x;
  int g = bx & 3, rt = bx >> 2;
  int r0 = rt * 4;
  #pragma unroll
  for (int t = 0; t < 4; ++t) {
    int idx = t * 256 + tid, r = idx >> 8, c = idx & 255;
    int row = r0 + r;
    ldsA[idx] = (row < NDIST) ? pe[row * 256 + c] : 0.f;
  }
  __syncthreads();
  int cg = tid & 63, ks = tid >> 6;
  const float4* wp = (const float4*)(W_fus + g * 65536) + ks * 4096 + cg;
  float acc[4][4];
  #pragma unroll
  for (int r = 0; r < 4; ++r) { acc[r][0] = acc[r][1] = acc[r][2] = acc[r][3] = 0.f; }
  #pragma unroll 4
  for (int kk = 0; kk < 64; ++kk) {
    float4 b4 = wp[kk * 64];
    #pragma unroll
    for (int r = 0; r < 4; ++r) {
      float a = ldsA[r * 256 + ks * 64 + kk];
      acc[r][0] = fmaf(a, b4.x, acc[r][0]);
      acc[r][1] = fmaf(a, b4.y, acc[r][1]);
      acc[r][2] = fmaf(a, b4.z, acc[r][2]);
      acc[r][3] = fmaf(a, b4.w, acc[r][3]);
    }
  }
  #pragma unroll
  for (int r = 0; r < 4; ++r)
    *(float4*)(red + ks * 1024 + r * 256 + cg * 4) =
        make_float4(acc[r][0], acc[r][1], acc[r][2], acc[r][3]);
  __syncthreads();
  float bb = (g == 0) ? b_fus[tid] : 0.f;
  #pragma unroll
  for (int r = 0; r < 4; ++r) {
    int row = r0 + r;
    if (row < NDIST) {
      float v = bb + red[r * 256 + tid] + red[1024 + r * 256 + tid] +
                red[2048 + r * 256 + tid] + red[3072 + r * 256 + tid];
      Tt[(g * NDIST + row) * 256 + tid] = __float2half(v);
    }
  }
}

// ======== projections q(->QU,QV), k, v ; grid (128, 3), 4 rows/block ========
__global__ void k_proj(const float* __restrict__ cur, const float* __restrict__ Wq,
                       const float* __restrict__ Wk, const float* __restrict__ Wv,
                       const float* __restrict__ bq, const float* __restrict__ bk,
                       const float* __restrict__ bv, const float* __restrict__ uu,
                       const float* __restrict__ vv, float* __restrict__ QU,
                       float* __restrict__ QV, float* __restrict__ Kb,
                       float* __restrict__ Vb) {
  __shared__ float ldsA[4 * 256];
  __shared__ float red[4 * 4 * 256];
  int tid = threadIdx.x;
  int r0 = blockIdx.x * 4;
  int by = blockIdx.y;
  const float* W = (by == 0) ? Wq : (by == 1) ? Wk : Wv;
  #pragma unroll
  for (int t = 0; t < 4; ++t) {
    int idx = t * 256 + tid, r = idx >> 8, c = idx & 255;
    ldsA[idx] = cur[(r0 + r) * 256 + c];
  }
  __syncthreads();
  int cg = tid & 63, ks = tid >> 6;
  const float4* wp = (const float4*)W + ks * 4096 + cg;
  float acc[4][4];
  #pragma unroll
  for (int r = 0; r < 4; ++r) { acc[r][0] = acc[r][1] = acc[r][2] = acc[r][3] = 0.f; }
  #pragma unroll 4
  for (int kk = 0; kk < 64; ++kk) {
    float4 b4 = wp[kk * 64];
    #pragma unroll
    for (int r = 0; r < 4; ++r) {
      float a = ldsA[r * 256 + ks * 64 + kk];
      acc[r][0] = fmaf(a, b4.x, acc[r][0]);
      acc[r][1] = fmaf(a, b4.y, acc[r][1]);
      acc[r][2] = fmaf(a, b4.z, acc[r][2]);
      acc[r][3] = fmaf(a, b4.w, acc[r][3]);
    }
  }
  #pragma unroll
  for (int r = 0; r < 4; ++r)
    *(float4*)(red + ks * 1024 + r * 256 + cg * 4) =
        make_float4(acc[r][0], acc[r][1], acc[r][2], acc[r][3]);
  __syncthreads();
  #pragma unroll
  for (int r = 0; r < 4; ++r) {
    int row = r0 + r;
    float s = red[r * 256 + tid] + red[1024 + r * 256 + tid] +
              red[2048 + r * 256 + tid] + red[3072 + r * 256 + tid];
    if (by == 0) {
      float base = s + bq[tid];
      QU[row * 256 + tid] = base + uu[tid];
      QV[row * 256 + tid] = base + vv[tid];
    } else if (by == 1) {
      Kb[row * 256 + tid] = s + bk[tid];
    } else {
      Vb[row * 256 + tid] = s + bv[tid];
    }
  }
}

// ======== P[bi][h*256+c] (f16) ; grid (128 rowtiles, 8 heads), 4 rows ========
__global__ void k_p(const float* __restrict__ QV, const float* __restrict__ Wr,
                    __half* __restrict__ P) {
  __shared__ float ldsB[32 * 257];  // [d][c] padded
  __shared__ float ldsA[4 * 32];
  int rt = blockIdx.x, h = blockIdx.y, tid = threadIdx.x;
  int r0 = rt * 4;
  #pragma unroll
  for (int pass = 0; pass < 8; ++pass) {
    int c = pass * 32 + (tid >> 3), q = tid & 7;
    float4 w4 = ((const float4*)(Wr + c * 256 + h * 32))[q];
    ldsB[(q * 4 + 0) * 257 + c] = w4.x;
    ldsB[(q * 4 + 1) * 257 + c] = w4.y;
    ldsB[(q * 4 + 2) * 257 + c] = w4.z;
    ldsB[(q * 4 + 3) * 257 + c] = w4.w;
  }
  if (tid < 128) {
    int r = tid >> 5, d = tid & 31;
    ldsA[r * 32 + d] = QV[(r0 + r) * 256 + h * 32 + d];
  }
  __syncthreads();
  int c = tid;
  float acc[4] = {0, 0, 0, 0};
  #pragma unroll 4
  for (int d = 0; d < 32; ++d) {
    float b = ldsB[d * 257 + c];
    #pragma unroll
    for (int r = 0; r < 4; ++r) acc[r] = fmaf(ldsA[r * 32 + d], b, acc[r]);
  }
  #pragma unroll
  for (int r = 0; r < 4; ++r) P[(r0 + r) * 2048 + h * 256 + c] = __float2half(acc[r]);
}

// ======== scores: AC + BD + mask -> SC[bi][h][j] ; grid (512, 8) ========
__global__ void k_score(const float* __restrict__ QU, const float* __restrict__ Kb,
                        const __half* __restrict__ P, const __half* __restrict__ Tt,
                        const int* __restrict__ pos_s, const int* __restrict__ pos_e,
                        const int* __restrict__ real_lengths, const int* __restrict__ lex_num,
                        float* __restrict__ SC) {
  __shared__ __align__(16) __half plh[2048];
  __shared__ float qu[256];
  __shared__ float scl[NH][32];
  int tid = threadIdx.x;
  int bi = blockIdx.x, b = bi >> 8, i = bi & 255;
  int jc = blockIdx.y;
  int rl = real_lengths[b] + lex_num[0];
  if (jc * 32 >= rl) {
    // whole j-chunk masked: write -1e15 (exp -> 0), skip all gather/math
    int h = tid >> 5, jj = tid & 31;
    SC[bi * 2048 + h * 256 + jc * 32 + jj] = -1e15f;
    return;
  }
  ((uint4*)plh)[tid] = ((const uint4*)(P + bi * 2048))[tid];
  qu[tid] = QU[bi * 256 + tid];
  __syncthreads();
  int jl = tid >> 3, cl = tid & 7;
  int j = jc * 32 + jl;
  int psi = pos_s[b * Sq + i], pei = pos_e[b * Sq + i];
  int psj = pos_s[b * Sq + j], pej = pos_e[b * Sq + j];
  const __half* t0 = Tt + (0 * NDIST + (psi - psj + 256)) * 256;
  const __half* t1 = Tt + (1 * NDIST + (psi - pej + 256)) * 256;
  const __half* t2 = Tt + (2 * NDIST + (pei - psj + 256)) * 256;
  const __half* t3 = Tt + (3 * NDIST + (pei - pej + 256)) * 256;
  __half2 z2 = __float2half2_rn(0.f);
  __half2 acc2[NH];
  #pragma unroll
  for (int h = 0; h < NH; ++h) acc2[h] = z2;
  #pragma unroll
  for (int ci = 0; ci < 4; ++ci) {
    int c0 = (ci * 8 + cl) * 8;
    H8 A0, A1, A2, A3;
    A0.u4 = *(const uint4*)(t0 + c0);
    A1.u4 = *(const uint4*)(t1 + c0);
    A2.u4 = *(const uint4*)(t2 + c0);
    A3.u4 = *(const uint4*)(t3 + c0);
    __half2 r2[4];
    #pragma unroll
    for (int p = 0; p < 4; ++p) {
      __half2 s = __hadd2(__hadd2(A0.h2[p], A1.h2[p]), __hadd2(A2.h2[p], A3.h2[p]));
      r2[p] = __hmul2(s, __hgt2(s, z2));   // half2 relu
    }
    #pragma unroll
    for (int h = 0; h < NH; ++h) {
      H8 Ph;
      Ph.u4 = *(const uint4*)(plh + h * 256 + c0);
      #pragma unroll
      for (int p = 0; p < 4; ++p) acc2[h] = __hfma2(r2[p], Ph.h2[p], acc2[h]);
    }
  }
  const float4* kp = (const float4*)(Kb + (b * Sq + j) * 256);
  float bd[NH];
  #pragma unroll
  for (int h = 0; h < NH; ++h) {
    bd[h] = __low2float(acc2[h]) + __high2float(acc2[h]);
    float4 k4 = kp[h * 8 + cl];
    float4 q4 = *(const float4*)(qu + h * 32 + cl * 4);
    bd[h] += k4.x * q4.x + k4.y * q4.y + k4.z * q4.z + k4.w * q4.w;
  }
  #pragma unroll
  for (int h = 0; h < NH; ++h) {
    bd[h] += __shfl_xor(bd[h], 1);
    bd[h] += __shfl_xor(bd[h], 2);
    bd[h] += __shfl_xor(bd[h], 4);
  }
  if (cl == 0) {
    #pragma unroll
    for (int h = 0; h < NH; ++h) scl[h][jl] = bd[h];
  }
  __syncthreads();
  int h = tid >> 5, jj = tid & 31;
  int j2 = jc * 32 + jj;
  SC[bi * 2048 + h * 256 + j2] = (j2 < rl) ? scl[h][jj] : -1e15f;
}

// ======== softmax + attn*V + residual + LN ; grid 512, block 256 ========
__global__ void k_smav_ln(const float* __restrict__ SC, const float* __restrict__ Vb,
                          const float* __restrict__ cur,
                          const int* __restrict__ real_lengths,
                          const int* __restrict__ lex_num, float* __restrict__ Y) {
  __shared__ float sc[2048];
  __shared__ float inv[NH];
  __shared__ float part[4 * 256];
  __shared__ float red2[4];
  int tid = threadIdx.x;
  int bi = blockIdx.x, b = bi >> 8;
  int rl = real_lengths[b] + lex_num[0];
  ((float4*)sc)[tid] = ((const float4*)(SC + bi * 2048))[tid];
  ((float4*)sc)[256 + tid] = ((const float4*)(SC + bi * 2048))[256 + tid];
  __syncthreads();
  {
    int h = tid >> 5, t = tid & 31;
    float mx = -INFINITY;
    #pragma unroll
    for (int m = 0; m < 8; ++m) mx = fmaxf(mx, sc[h * 256 + t + 32 * m]);
    #pragma unroll
    for (int sh = 16; sh >= 1; sh >>= 1) mx = fmaxf(mx, __shfl_xor(mx, sh));
    float sum = 0.f;
    #pragma unroll
    for (int m = 0; m < 8; ++m) {
      float e = __expf(sc[h * 256 + t + 32 * m] - mx);
      sc[h * 256 + t + 32 * m] = e;
      sum += e;
    }
    #pragma unroll
    for (int sh = 16; sh >= 1; sh >>= 1) sum += __shfl_xor(sum, sh);
    if (t == 0) inv[h] = 1.f / sum;
  }
  __syncthreads();
  {
    int n4 = tid & 63, jg = tid >> 6, h = n4 >> 3;
    float4 acc = make_float4(0.f, 0.f, 0.f, 0.f);
    if (jg * 64 < rl) {   // skip fully-masked j-chunks (their sc == 0 exactly)
      const float4* vp = (const float4*)(Vb + b * 65536) + n4;
      #pragma unroll 4
      for (int jj0 = 0; jj0 < 64; ++jj0) {
        int jj = jg * 64 + jj0;
        float s = sc[h * 256 + jj];
        float4 v4 = vp[jj * 64];
        acc.x = fmaf(s, v4.x, acc.x);
        acc.y = fmaf(s, v4.y, acc.y);
        acc.z = fmaf(s, v4.z, acc.z);
        acc.w = fmaf(s, v4.w, acc.w);
      }
    }
    *(float4*)(part + jg * 256 + n4 * 4) = acc;
  }
  __syncthreads();
  int n = tid;
  float o = part[n] + part[256 + n] + part[512 + n] + part[768 + n];
  float val = cur[bi * 256 + n] + o * inv[n >> 5];
  float ss = val;
  #pragma unroll
  for (int sh = 32; sh >= 1; sh >>= 1) ss += __shfl_xor(ss, sh);
  if ((tid & 63) == 0) red2[tid >> 6] = ss;
  __syncthreads();
  float mean = (red2[0] + red2[1] + red2[2] + red2[3]) * (1.f / 256.f);
  float d = val - mean;
  float s2 = d * d;
  __syncthreads();
  #pragma unroll
  for (int sh = 32; sh >= 1; sh >>= 1) s2 += __shfl_xor(s2, sh);
  if ((tid & 63) == 0) red2[tid >> 6] = s2;
  __syncthreads();
  float var = (red2[0] + red2[1] + red2[2] + red2[3]) * (1.f / 256.f);
  Y[bi * 256 + n] = d * rsqrtf(var + 1e-5f);
}

// ======== FFN1: relu(Y@W1+b1) ; grid (128, 4 colchunks), 4 rows ========
__global__ void k_ffn1(const float* __restrict__ Y, const float* __restrict__ W1,
                       const float* __restrict__ b1, float* __restrict__ H1) {
  __shared__ float ldsA[4 * 256];
  __shared__ float red[4 * 4 * 256];
  int tid = threadIdx.x;
  int r0 = blockIdx.x * 4, by = blockIdx.y;
  #pragma unroll
  for (int t = 0; t < 4; ++t) {
    int idx = t * 256 + tid, r = idx >> 8, c = idx & 255;
    ldsA[idx] = Y[(r0 + r) * 256 + c];
  }
  __syncthreads();
  int cg = tid & 63, ks = tid >> 6;
  const float4* wp = (const float4*)(W1 + by * 256) + ks * 16384 + cg;
  float acc[4][4];
  #pragma unroll
  for (int r = 0; r < 4; ++r) { acc[r][0] = acc[r][1] = acc[r][2] = acc[r][3] = 0.f; }
  #pragma unroll 4
  for (int kk = 0; kk < 64; ++kk) {
    float4 b4 = wp[kk * 256];
    #pragma unroll
    for (int r = 0; r < 4; ++r) {
      float a = ldsA[r * 256 + ks * 64 + kk];
      acc[r][0] = fmaf(a, b4.x, acc[r][0]);
      acc[r][1] = fmaf(a, b4.y, acc[r][1]);
      acc[r][2] = fmaf(a, b4.z, acc[r][2]);
      acc[r][3] = fmaf(a, b4.w, acc[r][3]);
    }
  }
  #pragma unroll
  for (int r = 0; r < 4; ++r)
    *(float4*)(red + ks * 1024 + r * 256 + cg * 4) =
        make_float4(acc[r][0], acc[r][1], acc[r][2], acc[r][3]);
  __syncthreads();
  int n = by * 256 + tid;
  float bb = b1[n];
  #pragma unroll
  for (int r = 0; r < 4; ++r) {
    float s = bb + red[r * 256 + tid] + red[1024 + r * 256 + tid] +
              red[2048 + r * 256 + tid] + red[3072 + r * 256 + tid];
    H1[(r0 + r) * 1024 + n] = fmaxf(s, 0.f);
  }
}

// ======== FFN2 partial: grid (128 rowtiles, 4 kchunks), 4 rows ========
__global__ void k_ffn2(const float* __restrict__ H1, const float* __restrict__ W2,
                       float* __restrict__ Pbuf) {
  __shared__ float ldsA[4 * 256];
  __shared__ float red[4 * 4 * 256];
  int tid = threadIdx.x;
  int r0 = blockIdx.x * 4, by = blockIdx.y;
  #pragma unroll
  for (int t = 0; t < 4; ++t) {
    int idx = t * 256 + tid, r = idx >> 8, c = idx & 255;
    ldsA[idx] = H1[(r0 + r) * 1024 + by * 256 + c];
  }
  __syncthreads();
  int cg = tid & 63, ks = tid >> 6;
  const float4* wp = (const float4*)(W2 + by * 256 * 256) + ks * 4096 + cg;
  float acc[4][4];
  #pragma unroll
  for (int r = 0; r < 4; ++r) { acc[r][0] = acc[r][1] = acc[r][2] = acc[r][3] = 0.f; }
  #pragma unroll 4
  for (int kk = 0; kk < 64; ++kk) {
    float4 b4 = wp[kk * 64];
    #pragma unroll
    for (int r = 0; r < 4; ++r) {
      float a = ldsA[r * 256 + ks * 64 + kk];
      acc[r][0] = fmaf(a, b4.x, acc[r][0]);
      acc[r][1] = fmaf(a, b4.y, acc[r][1]);
      acc[r][2] = fmaf(a, b4.z, acc[r][2]);
      acc[r][3] = fmaf(a, b4.w, acc[r][3]);
    }
  }
  #pragma unroll
  for (int r = 0; r < 4; ++r)
    *(float4*)(red + ks * 1024 + r * 256 + cg * 4) =
        make_float4(acc[r][0], acc[r][1], acc[r][2], acc[r][3]);
  __syncthreads();
  #pragma unroll
  for (int r = 0; r < 4; ++r) {
    float s = red[r * 256 + tid] + red[1024 + r * 256 + tid] +
              red[2048 + r * 256 + tid] + red[3072 + r * 256 + tid];
    Pbuf[by * 131072 + (r0 + r) * 256 + tid] = s;
  }
}

// ======== FFN2 reduce + relu + residual + LN ; grid 512, block 256 ========
__global__ void k_ffn2red_ln(const float* __restrict__ Pbuf, const float* __restrict__ b2,
                             const float* __restrict__ Y, float* __restrict__ O) {
  __shared__ float red2[4];
  int m = blockIdx.x, tid = threadIdx.x;
  float s = Pbuf[m * 256 + tid] + Pbuf[131072 + m * 256 + tid] +
            Pbuf[262144 + m * 256 + tid] + Pbuf[393216 + m * 256 + tid] + b2[tid];
  float val = fmaxf(s, 0.f) + Y[m * 256 + tid];
  float ss = val;
  #pragma unroll
  for (int sh = 32; sh >= 1; sh >>= 1) ss += __shfl_xor(ss, sh);
  if ((tid & 63) == 0) red2[tid >> 6] = ss;
  __syncthreads();
  float mean = (red2[0] + red2[1] + red2[2] + red2[3]) * (1.f / 256.f);
  float d = val - mean;
  float s2 = d * d;
  __syncthreads();
  #pragma unroll
  for (int sh = 32; sh >= 1; sh >>= 1) s2 += __shfl_xor(s2, sh);
  if ((tid & 63) == 0) red2[tid >> 6] = s2;
  __syncthreads();
  float var = (red2[0] + red2[1] + red2[2] + red2[3]) * (1.f / 256.f);
  O[m * 256 + tid] = d * rsqrtf(var + 1e-5f);
}

extern "C" void kernel_launch(void* const* d_in, const int* in_sizes, int n_in,
                              void* d_out, int out_size, void* d_ws, size_t ws_size,
                              hipStream_t stream) {
  const float* x            = (const float*)d_in[0];
  const int*   pos_s        = (const int*)d_in[1];
  const int*   pos_e        = (const int*)d_in[2];
  const int*   real_lengths = (const int*)d_in[3];
  const int*   lex_num      = (const int*)d_in[4];
  const float* pe           = (const float*)d_in[5];
  const float* W_fus        = (const float*)d_in[6];
  const float* b_fus        = (const float*)d_in[7];
  const float* Wq           = (const float*)d_in[8];
  const float* bq           = (const float*)d_in[9];
  const float* Wk           = (const float*)d_in[10];
  const float* bk           = (const float*)d_in[11];
  const float* Wv           = (const float*)d_in[12];
  const float* bv           = (const float*)d_in[13];
  const float* Wr           = (const float*)d_in[14];
  // br dropped: per-(b,i,h) constant score shift, softmax-invariant
  const float* u            = (const float*)d_in[16];
  const float* v            = (const float*)d_in[17];
  const float* W1           = (const float*)d_in[18];
  const float* b1           = (const float*)d_in[19];
  const float* W2           = (const float*)d_in[20];
  const float* b2           = (const float*)d_in[21];
  float* out = (float*)d_out;

  float* ws = (float*)d_ws;
  __half* Tt = (__half*)ws;                 // 525312 halfs -> 262656 floats
  float* QU  = ws + 262656;
  float* QV  = QU + 131072;
  float* Kb  = QV + 131072;
  float* Vb  = Kb + 131072;
  __half* P  = (__half*)(Vb + 131072);      // 1048576 halfs -> 524288 floats
  float* SC  = Vb + 131072 + 524288;        // 1048576 floats
  float* Y   = SC + 1048576;
  float* C1  = Y + 131072;
  float* H1  = C1 + 131072;                 // 524288
  float* Pb  = H1 + 524288;                 // 524288

  k_tables<<<516, 256, 0, stream>>>(pe, W_fus, b_fus, Tt);

  for (int l = 0; l < 2; ++l) {
    const float* cur = l ? C1 : x;
    float* outb = l ? out : C1;
    const int wo = l * 65536, bo = l * 256;
    k_proj<<<dim3(128, 3), 256, 0, stream>>>(cur, Wq + wo, Wk + wo, Wv + wo,
                                             bq + bo, bk + bo, bv + bo, u + bo, v + bo,
                                             QU, QV, Kb, Vb);
    k_p<<<dim3(128, 8), 256, 0, stream>>>(QV, Wr + wo, P);
    k_score<<<dim3(512, 8), 256, 0, stream>>>(QU, Kb, P, Tt, pos_s, pos_e,
                                              real_lengths, lex_num, SC);
    k_smav_ln<<<512, 256, 0, stream>>>(SC, Vb, cur, real_lengths, lex_num, Y);
    k_ffn1<<<dim3(128, 4), 256, 0, stream>>>(Y, W1 + l * 262144, b1 + l * 1024, H1);
    k_ffn2<<<dim3(128, 4), 256, 0, stream>>>(H1, W2 + l * 262144, Pb);
    k_ffn2red_ln<<<512, 256, 0, stream>>>(Pb, b2 + bo, Y, outb);
  }
}